// Round 1
// baseline (90.926 us; speedup 1.0000x reference)
//
#include <hip/hip_runtime.h>

#define DD 2048
#define BB 16

__global__ __launch_bounds__(256) void gates_kernel(
    const float* __restrict__ xt, const float* __restrict__ h,
    const float* __restrict__ Wa, const float* __restrict__ Wx,
    const float* __restrict__ ba, const float* __restrict__ bx,
    const float* __restrict__ Lam,
    float* __restrict__ u_ws, float* __restrict__ dv_ws)
{
    const int j    = blockIdx.x;      // output column (0..2047)
    const int t    = threadIdx.x;     // 256 threads = 4 waves
    const int wave = t >> 6;
    const int lane = t & 63;
    const int gate = wave >> 1;       // 0 -> Wa, 1 -> Wx
    const int half = wave & 1;        // each gate's K-range split across 2 waves

    const float4* W4 = (const float4*)(gate ? Wx : Wa);
    const float4* x4 = (const float4*)xt;

    float acc[BB];
#pragma unroll
    for (int b = 0; b < BB; ++b) acc[b] = 0.f;

    // W row j: 512 float4. This wave covers half*256 .. half*256+255, 4 iters of 64 lanes.
#pragma unroll
    for (int it = 0; it < 4; ++it) {
        const int k4 = half * 256 + it * 64 + lane;
        const float4 w = W4[j * (DD / 4) + k4];
#pragma unroll
        for (int b = 0; b < BB; ++b) {
            const float4 x = x4[b * (DD / 4) + k4];
            acc[b] = fmaf(w.x, x.x, acc[b]);
            acc[b] = fmaf(w.y, x.y, acc[b]);
            acc[b] = fmaf(w.z, x.z, acc[b]);
            acc[b] = fmaf(w.w, x.w, acc[b]);
        }
    }

    // wave-level reduction (64 lanes) for each of the 16 batch accumulators
#pragma unroll
    for (int b = 0; b < BB; ++b) {
        float v = acc[b];
        for (int off = 32; off; off >>= 1) v += __shfl_down(v, off, 64);
        acc[b] = v;   // valid on lane 0
    }

    __shared__ float red[4][BB];
    if (lane == 0) {
#pragma unroll
        for (int b = 0; b < BB; ++b) red[wave][b] = acc[b];
    }
    __syncthreads();

    if (t < BB) {
        const int b = t;
        const float rA = red[0][b] + red[1][b] + ba[j];
        const float rX = red[2][b] + red[3][b] + bx[j];
        const float rt  = 1.f / (1.f + expf(-rA));
        const float itg = 1.f / (1.f + expf(-rX));
        const float log_a = -log1pf(expf(-Lam[j]));     // -softplus(-Lam)
        const float a = expf(log_a * rt * 0.125f);      // / C, C = 8
        const float u = sqrtf(fmaxf(0.f, 1.f - a * a)) * (itg * xt[b * DD + j]);
        const float dv = fmaf(a, h[b * DD + j], u);
        u_ws[b * DD + j]  = u;
        dv_ws[b * DD + j] = dv;
    }
}

__global__ __launch_bounds__(256) void fill_kernel(
    const float* __restrict__ u_ws, const float* __restrict__ dv_ws,
    float4* __restrict__ out)
{
    const int total = BB * DD * (DD / 4);   // 16,777,216 float4
    const int stride = gridDim.x * 256;
    for (int idx = blockIdx.x * 256 + threadIdx.x; idx < total; idx += stride) {
        const int j4 = idx & (DD / 4 - 1);   // 0..511
        const int bi = idx >> 9;             // b*D + i
        const int i  = bi & (DD - 1);
        const int b  = bi >> 11;
        float4 v = ((const float4*)u_ws)[(b << 9) + j4];
        if ((i >> 2) == j4) {                // this float4 contains the diagonal
            ((float*)&v)[i & 3] = dv_ws[(b << 11) + i];
        }
        out[idx] = v;
    }
}

extern "C" void kernel_launch(void* const* d_in, const int* in_sizes, int n_in,
                              void* d_out, int out_size, void* d_ws, size_t ws_size,
                              hipStream_t stream) {
    const float* xt  = (const float*)d_in[0];
    const float* h   = (const float*)d_in[1];
    const float* Wa  = (const float*)d_in[2];
    const float* Wx  = (const float*)d_in[3];
    const float* ba  = (const float*)d_in[4];
    const float* bx  = (const float*)d_in[5];
    const float* Lam = (const float*)d_in[6];

    float* u_ws  = (float*)d_ws;             // [B, D]
    float* dv_ws = u_ws + BB * DD;           // [B, D]

    gates_kernel<<<DD, 256, 0, stream>>>(xt, h, Wa, Wx, ba, bx, Lam, u_ws, dv_ws);
    fill_kernel<<<2048, 256, 0, stream>>>(u_ws, dv_ws, (float4*)d_out);
}

// Round 2
// 71.730 us; speedup vs baseline: 1.2676x; 1.2676x over previous
//
#include <hip/hip_runtime.h>

#define DD 2048
#define BB 16

// ---------------------------------------------------------------------------
// gates: compute u[b,j] and diag value dv[b,j] = a*h + u.
// C[j, b] = sum_k W[j,k] * xt[b,k]  for both Wa and Wx, sharing the xt loads.
// Block = 2 output columns (j0, j0+1); wave = (jj, K-half); both gates/wave.
// ---------------------------------------------------------------------------
__global__ __launch_bounds__(256) void gates_kernel(
    const float* __restrict__ xt, const float* __restrict__ h,
    const float* __restrict__ Wa, const float* __restrict__ Wx,
    const float* __restrict__ ba, const float* __restrict__ bx,
    const float* __restrict__ Lam,
    float* __restrict__ u_ws, float* __restrict__ dv_ws)
{
    const int j0   = blockIdx.x * 2;
    const int t    = threadIdx.x;
    const int wave = t >> 6;
    const int lane = t & 63;
    const int jj   = wave >> 1;       // which of the 2 columns
    const int half = wave & 1;        // K-half

    const int j = j0 + jj;
    const float4* x4  = (const float4*)xt;
    const float4* Wa4 = (const float4*)Wa + (size_t)j * (DD / 4);
    const float4* Wx4 = (const float4*)Wx + (size_t)j * (DD / 4);

    float accA[BB], accX[BB];
#pragma unroll
    for (int b = 0; b < BB; ++b) { accA[b] = 0.f; accX[b] = 0.f; }

    // K-half = 256 float4 -> 4 iterations of 64 lanes
#pragma unroll
    for (int it = 0; it < 4; ++it) {
        const int k4 = half * 256 + it * 64 + lane;
        const float4 wa = Wa4[k4];
        const float4 wx = Wx4[k4];
#pragma unroll
        for (int b = 0; b < BB; ++b) {
            const float4 x = x4[b * (DD / 4) + k4];
            accA[b] = fmaf(wa.x, x.x, accA[b]);
            accA[b] = fmaf(wa.y, x.y, accA[b]);
            accA[b] = fmaf(wa.z, x.z, accA[b]);
            accA[b] = fmaf(wa.w, x.w, accA[b]);
            accX[b] = fmaf(wx.x, x.x, accX[b]);
            accX[b] = fmaf(wx.y, x.y, accX[b]);
            accX[b] = fmaf(wx.z, x.z, accX[b]);
            accX[b] = fmaf(wx.w, x.w, accX[b]);
        }
    }

    // 64-lane butterfly reduction; result valid on lane 0
#pragma unroll
    for (int b = 0; b < BB; ++b) {
        float a = accA[b], x = accX[b];
        for (int m = 32; m; m >>= 1) { a += __shfl_xor(a, m, 64); x += __shfl_xor(x, m, 64); }
        accA[b] = a; accX[b] = x;
    }

    __shared__ float red[2][2][2][BB];   // [jj][half][gate][b]
    if (lane == 0) {
#pragma unroll
        for (int b = 0; b < BB; ++b) {
            red[jj][half][0][b] = accA[b];
            red[jj][half][1][b] = accX[b];
        }
    }
    __syncthreads();

    if (t < 32) {
        const int tj = t >> 4;
        const int b  = t & 15;
        const int jc = j0 + tj;
        const float rA = red[tj][0][0][b] + red[tj][1][0][b] + ba[jc];
        const float rX = red[tj][0][1][b] + red[tj][1][1][b] + bx[jc];
        const float rt  = 1.f / (1.f + expf(-rA));
        const float itg = 1.f / (1.f + expf(-rX));
        const float log_a = -log1pf(expf(-Lam[jc]));    // -softplus(-Lam)
        const float a = expf(log_a * rt * 0.125f);      // / C, C = 8
        const float u = sqrtf(fmaxf(0.f, 1.f - a * a)) * (itg * xt[b * DD + jc]);
        const float dv = fmaf(a, h[b * DD + jc], u);
        u_ws[b * DD + jc]  = u;
        dv_ws[b * DD + jc] = dv;
    }
}

// ---------------------------------------------------------------------------
// fill: out[b,i,:] = u[b,:] with out[b,i,i] = dv[b,i].
// Block = (b, group of 16 rows). Each thread holds its 2 u float4s in
// registers and streams 32 coalesced stores. No per-element loads.
// ---------------------------------------------------------------------------
__global__ __launch_bounds__(256) void fill_kernel(
    const float4* __restrict__ u4, const float* __restrict__ dv,
    float4* __restrict__ out)
{
    const int blk = blockIdx.x;       // 0..2047
    const int b   = blk >> 7;         // 0..15
    const int ig  = blk & 127;        // 0..127
    const int i0  = ig << 4;          // 16 rows starting here
    const int t   = threadIdx.x;

    const float4 v0 = u4[(b << 9) + t];         // j4 = t
    const float4 v1 = u4[(b << 9) + 256 + t];   // j4 = 256 + t

    float4* orow = out + ((size_t)b << 20) + ((size_t)i0 << 9);
#pragma unroll
    for (int r = 0; r < 16; ++r) {
        const int i   = i0 + r;
        const int dj4 = i >> 2;
        float4 w0 = v0, w1 = v1;
        if (dj4 == t) {
            ((float*)&w0)[i & 3] = dv[(b << 11) + i];
        } else if (dj4 == 256 + t) {
            ((float*)&w1)[i & 3] = dv[(b << 11) + i];
        }
        orow[t]       = w0;
        orow[256 + t] = w1;
        orow += DD / 4;
    }
}

extern "C" void kernel_launch(void* const* d_in, const int* in_sizes, int n_in,
                              void* d_out, int out_size, void* d_ws, size_t ws_size,
                              hipStream_t stream) {
    const float* xt  = (const float*)d_in[0];
    const float* h   = (const float*)d_in[1];
    const float* Wa  = (const float*)d_in[2];
    const float* Wx  = (const float*)d_in[3];
    const float* ba  = (const float*)d_in[4];
    const float* bx  = (const float*)d_in[5];
    const float* Lam = (const float*)d_in[6];

    float* u_ws  = (float*)d_ws;             // [B, D]
    float* dv_ws = u_ws + BB * DD;           // [B, D]

    gates_kernel<<<DD / 2, 256, 0, stream>>>(xt, h, Wa, Wx, ba, bx, Lam, u_ws, dv_ws);
    fill_kernel<<<BB * (DD / 16), 256, 0, stream>>>((const float4*)u_ws, dv_ws, (float4*)d_out);
}